// Round 1
// baseline (2681.865 us; speedup 1.0000x reference)
//
#include <hip/hip_runtime.h>
#include <math.h>

#define BATCH 65536
#define KIN   784
#define HD    768

__device__ __forceinline__ float frelu(float x){ return x > 0.f ? x : 0.f; }

// ---------------------------------------------------------------------------
// fp32 tiled GEMM: out[M,N] = A[M,K] @ W[K,N]
// MODE 0: C = A@W + bias  (GEMM1: x@W1+b1 -> h)
// MODE 1: A' = relu(A*scale+shift) per-column (BN apply on h);
//         a = relu(A'@W + bias); epilogue: domacc[row][d] += sum_n a*Wd2[n][d]
//         (fp64, wave shuffle-reduced, global fp64 atomics). C not written.
// Tiles BM=128, BN=64, BK=16; 256 threads; micro-tile 8x4.
// Grid: 6144 blocks, swizzled so the 12 col-blocks of one row-panel share an XCD.
// ---------------------------------------------------------------------------
template<int MODE>
__global__ __launch_bounds__(256)
void gemm_fp32(const float* __restrict__ A, const float* __restrict__ W,
               const float* __restrict__ bias, float* __restrict__ C,
               const float* __restrict__ scale, const float* __restrict__ shift,
               const float* __restrict__ Wd2, double* __restrict__ domacc,
               int K, int ldA)
{
    __shared__ float As[16][128];
    __shared__ float Bs[16][64];

    int bid = blockIdx.x;
    int q = bid >> 3, rsd = bid & 7;
    int mb = rsd + ((q / 12) << 3);   // 0..511 ; same mb => same bid%8 (same XCD slot)
    int nb = q - (q / 12) * 12;       // 0..11
    int m0 = mb << 7, n0 = nb << 6;

    int tid = threadIdx.x;
    int tc = tid & 15, tr = tid >> 4;

    int arow = tid >> 1;          // 0..127
    int akp  = (tid & 1) << 3;    // 0 or 8
    int brow = tid >> 4;          // 0..15
    int bcol = (tid & 15) << 2;   // 0..60

    const float* aptr = A + (size_t)(m0 + arow) * ldA + akp;
    const float* wptr = W + (size_t)brow * HD + n0 + bcol;

    float acc[8][4];
    #pragma unroll
    for (int i = 0; i < 8; i++)
        #pragma unroll
        for (int j = 0; j < 4; j++) acc[i][j] = 0.f;

    for (int k0 = 0; k0 < K; k0 += 16) {
        float4 a0 = *(const float4*)(aptr + k0);
        float4 a1 = *(const float4*)(aptr + k0 + 4);
        if (MODE == 1) {
            int kb = k0 + akp;
            a0.x = frelu(a0.x * scale[kb+0] + shift[kb+0]);
            a0.y = frelu(a0.y * scale[kb+1] + shift[kb+1]);
            a0.z = frelu(a0.z * scale[kb+2] + shift[kb+2]);
            a0.w = frelu(a0.w * scale[kb+3] + shift[kb+3]);
            a1.x = frelu(a1.x * scale[kb+4] + shift[kb+4]);
            a1.y = frelu(a1.y * scale[kb+5] + shift[kb+5]);
            a1.z = frelu(a1.z * scale[kb+6] + shift[kb+6]);
            a1.w = frelu(a1.w * scale[kb+7] + shift[kb+7]);
        }
        float4 b4 = *(const float4*)(wptr + (size_t)k0 * HD);

        __syncthreads();
        As[akp+0][arow] = a0.x; As[akp+1][arow] = a0.y;
        As[akp+2][arow] = a0.z; As[akp+3][arow] = a0.w;
        As[akp+4][arow] = a1.x; As[akp+5][arow] = a1.y;
        As[akp+6][arow] = a1.z; As[akp+7][arow] = a1.w;
        *(float4*)&Bs[brow][bcol] = b4;
        __syncthreads();

        #pragma unroll
        for (int k = 0; k < 16; k++) {
            float af[8], bf[4];
            *(float4*)&af[0] = *(const float4*)&As[k][tr << 3];
            *(float4*)&af[4] = *(const float4*)&As[k][(tr << 3) + 4];
            *(float4*)&bf[0] = *(const float4*)&Bs[k][tc << 2];
            #pragma unroll
            for (int i = 0; i < 8; i++)
                #pragma unroll
                for (int j = 0; j < 4; j++) acc[i][j] += af[i] * bf[j];
        }
    }

    if (MODE == 0) {
        float4 bb4 = *(const float4*)(bias + n0 + (tc << 2));
        #pragma unroll
        for (int i = 0; i < 8; i++) {
            int row = m0 + (tr << 3) + i;
            float4 o;
            o.x = acc[i][0] + bb4.x;
            o.y = acc[i][1] + bb4.y;
            o.z = acc[i][2] + bb4.z;
            o.w = acc[i][3] + bb4.w;
            *(float4*)(C + (size_t)row * HD + n0 + (tc << 2)) = o;
        }
    } else {
        float4 bb4 = *(const float4*)(bias + n0 + (tc << 2));
        int n = n0 + (tc << 2);
        float w00=Wd2[(n+0)*3+0], w01=Wd2[(n+0)*3+1], w02=Wd2[(n+0)*3+2];
        float w10=Wd2[(n+1)*3+0], w11=Wd2[(n+1)*3+1], w12=Wd2[(n+1)*3+2];
        float w20=Wd2[(n+2)*3+0], w21=Wd2[(n+2)*3+1], w22=Wd2[(n+2)*3+2];
        float w30=Wd2[(n+3)*3+0], w31=Wd2[(n+3)*3+1], w32=Wd2[(n+3)*3+2];
        #pragma unroll
        for (int i = 0; i < 8; i++) {
            float a0 = frelu(acc[i][0] + bb4.x);
            float a1 = frelu(acc[i][1] + bb4.y);
            float a2 = frelu(acc[i][2] + bb4.z);
            float a3 = frelu(acc[i][3] + bb4.w);
            double d0 = (double)a0*w00 + (double)a1*w10 + (double)a2*w20 + (double)a3*w30;
            double d1 = (double)a0*w01 + (double)a1*w11 + (double)a2*w21 + (double)a3*w31;
            double d2 = (double)a0*w02 + (double)a1*w12 + (double)a2*w22 + (double)a3*w32;
            #pragma unroll
            for (int off = 1; off < 16; off <<= 1) {
                d0 += __shfl_xor(d0, off, 64);
                d1 += __shfl_xor(d1, off, 64);
                d2 += __shfl_xor(d2, off, 64);
            }
            if (tc == 0) {
                int row = m0 + (tr << 3) + i;
                atomicAdd(&domacc[(size_t)row*3+0], d0);
                atomicAdd(&domacc[(size_t)row*3+1], d1);
                atomicAdd(&domacc[(size_t)row*3+2], d2);
            }
        }
    }
}

// ---- BN statistics: deterministic two-stage fp64 column reduction ----------
__global__ __launch_bounds__(256)
void bnstats(const float* __restrict__ h, double* __restrict__ s1, double* __restrict__ s2)
{
    int b = blockIdx.x, t = threadIdx.x;
    const float* base = h + (size_t)b * 256 * HD;
    double a0=0,a1=0,a2=0,q0=0,q1=0,q2=0;
    for (int r = 0; r < 256; r++) {
        const float* row = base + (size_t)r * HD;
        float v0 = row[t], v1 = row[t+256], v2 = row[t+512];
        a0 += v0; a1 += v1; a2 += v2;
        q0 += (double)v0 * (double)v0;
        q1 += (double)v1 * (double)v1;
        q2 += (double)v2 * (double)v2;
    }
    s1[(size_t)b*HD + t      ] = a0; s1[(size_t)b*HD + t + 256] = a1; s1[(size_t)b*HD + t + 512] = a2;
    s2[(size_t)b*HD + t      ] = q0; s2[(size_t)b*HD + t + 256] = q1; s2[(size_t)b*HD + t + 512] = q2;
}

__global__ void bnfinal(const double* __restrict__ s1, const double* __restrict__ s2,
                        const float* __restrict__ gamma, const float* __restrict__ beta,
                        float* __restrict__ scale, float* __restrict__ shift)
{
    int c = blockIdx.x * 256 + threadIdx.x;
    if (c >= HD) return;
    double S = 0, Q = 0;
    for (int b = 0; b < 256; b++) { S += s1[(size_t)b*HD + c]; Q += s2[(size_t)b*HD + c]; }
    double mu  = S * (1.0 / 65536.0);
    double var = Q * (1.0 / 65536.0) - mu * mu;
    double inv = 1.0 / sqrt(var + 1e-5);
    double sc  = inv * (double)gamma[c];
    double sh  = (double)beta[c] - mu * sc;
    scale[c] = (float)sc;
    shift[c] = (float)sh;
}

// ---- dom_out finalize: +bd2, write output, fp64 argmax, bucket by domain ---
__global__ __launch_bounds__(256)
void domfinal(const double* __restrict__ domacc, const float* __restrict__ bd2,
              float* __restrict__ outdom, int* __restrict__ cnt, int* __restrict__ lists)
{
    int r = blockIdx.x * 256 + threadIdx.x;
    double v0 = domacc[(size_t)r*3+0] + (double)bd2[0];
    double v1 = domacc[(size_t)r*3+1] + (double)bd2[1];
    double v2 = domacc[(size_t)r*3+2] + (double)bd2[2];
    outdom[(size_t)r*3+0] = (float)v0;
    outdom[(size_t)r*3+1] = (float)v1;
    outdom[(size_t)r*3+2] = (float)v2;
    int p = 0; double best = v0;
    if (v1 > best) { best = v1; p = 1; }
    if (v2 > best) { best = v2; p = 2; }
    int pos = atomicAdd(&cnt[p], 1);
    lists[(size_t)p*BATCH + pos] = r;
}

// ---- expert MLP: 32 same-domain rows per block, Wa staged through LDS ------
__global__ __launch_bounds__(256)
void expert_kernel(const float* __restrict__ h, const float* __restrict__ scale, const float* __restrict__ shift,
                   const int* __restrict__ cnt, const int* __restrict__ lists,
                   const float* __restrict__ Wa, const float* __restrict__ ba,
                   const float* __restrict__ Wb, const float* __restrict__ bb,
                   float* __restrict__ outs)
{
    int d = blockIdx.y;
    int start = blockIdx.x * 32;
    int count = cnt[d];
    if (start >= count) return;
    int nrows = count - start; if (nrows > 32) nrows = 32;

    __shared__ int   rowidx[32];
    __shared__ float fs[32][68];     // feat chunk, padded vs bank conflicts
    __shared__ float wsa[64][64];    // Wa chunk
    __shared__ float hid[32][64];

    int tid = threadIdx.x;
    if (tid < 32) {
        int i = tid < nrows ? tid : (nrows - 1);
        rowidx[tid] = lists[(size_t)d*BATCH + start + i];
    }
    __syncthreads();

    int rr = tid >> 3;       // 0..31 (row)
    int g  = tid & 7;        // 0..7  (8-wide hid group)
    int fcol = g << 3;

    float hacc[8] = {0,0,0,0,0,0,0,0};

    for (int k0 = 0; k0 < HD; k0 += 64) {
        {   // stage feat chunk [32][64]
            int row = rowidx[rr];
            const float* hp  = h + (size_t)row*HD + k0 + fcol;
            const float* scp = scale + k0 + fcol;
            const float* shp = shift + k0 + fcol;
            float4 v0 = *(const float4*)hp;
            float4 v1 = *(const float4*)(hp + 4);
            fs[rr][fcol+0] = frelu(v0.x*scp[0]+shp[0]);
            fs[rr][fcol+1] = frelu(v0.y*scp[1]+shp[1]);
            fs[rr][fcol+2] = frelu(v0.z*scp[2]+shp[2]);
            fs[rr][fcol+3] = frelu(v0.w*scp[3]+shp[3]);
            fs[rr][fcol+4] = frelu(v1.x*scp[4]+shp[4]);
            fs[rr][fcol+5] = frelu(v1.y*scp[5]+shp[5]);
            fs[rr][fcol+6] = frelu(v1.z*scp[6]+shp[6]);
            fs[rr][fcol+7] = frelu(v1.w*scp[7]+shp[7]);
        }
        #pragma unroll
        for (int rep = 0; rep < 4; rep++) {   // stage Wa chunk [64][64]
            int idx = rep * 256 + tid;
            int kk = idx >> 4;
            int f4 = (idx & 15) << 2;
            *(float4*)&wsa[kk][f4] = *(const float4*)(Wa + ((size_t)d*HD + k0 + kk)*64 + f4);
        }
        __syncthreads();
        #pragma unroll 8
        for (int kk = 0; kk < 64; kk++) {
            float fv = fs[rr][kk];
            const float* wrow = &wsa[kk][g << 3];
            float4 w0 = *(const float4*)wrow;
            float4 w1 = *(const float4*)(wrow + 4);
            hacc[0] += fv*w0.x; hacc[1] += fv*w0.y; hacc[2] += fv*w0.z; hacc[3] += fv*w0.w;
            hacc[4] += fv*w1.x; hacc[5] += fv*w1.y; hacc[6] += fv*w1.z; hacc[7] += fv*w1.w;
        }
        __syncthreads();
    }

    #pragma unroll
    for (int j = 0; j < 8; j++) {
        float v = hacc[j] + ba[d*64 + fcol + j];
        hid[rr][fcol + j] = frelu(v);
    }
    __syncthreads();

    for (int o = tid; o < 320; o += 256) {
        int r2 = o / 10, c = o - r2*10;
        if (r2 < nrows) {
            float s = 0.f;
            #pragma unroll 16
            for (int l = 0; l < 64; l++) s += hid[r2][l] * Wb[((size_t)d*64 + l)*10 + c];
            outs[(size_t)rowidx[r2]*10 + c] = s + bb[d*10 + c];
        }
    }
}

// ---------------------------------------------------------------------------
extern "C" void kernel_launch(void* const* d_in, const int* in_sizes, int n_in,
                              void* d_out, int out_size, void* d_ws, size_t ws_size,
                              hipStream_t stream)
{
    const float* x     = (const float*)d_in[0];
    const float* W1    = (const float*)d_in[1];
    const float* b1    = (const float*)d_in[2];
    const float* gamma = (const float*)d_in[3];
    const float* beta  = (const float*)d_in[4];
    const float* Wd1   = (const float*)d_in[5];
    const float* bd1   = (const float*)d_in[6];
    const float* Wd2   = (const float*)d_in[7];
    const float* bd2   = (const float*)d_in[8];
    const float* Wa    = (const float*)d_in[9];
    const float* ba    = (const float*)d_in[10];
    const float* Wb    = (const float*)d_in[11];
    const float* bb    = (const float*)d_in[12];

    float* out    = (float*)d_out;
    float* outs   = out;                          // [B,10]
    float* outdom = out + (size_t)BATCH * 10;     // [B,3]

    char* ws = (char*)d_ws;
    size_t off = 0;
    float*  h      = (float*)(ws + off);  off += (size_t)BATCH * HD * 4;   // 201.3 MB
    double* s1     = (double*)(ws + off); off += (size_t)256 * HD * 8;
    double* s2     = (double*)(ws + off); off += (size_t)256 * HD * 8;
    float*  scale  = (float*)(ws + off);  off += HD * 4;
    float*  shift  = (float*)(ws + off);  off += HD * 4;
    size_t zoff = off;
    double* domacc = (double*)(ws + off); off += (size_t)BATCH * 3 * 8;
    int*    cnt    = (int*)(ws + off);    off += 16;
    size_t zbytes = off - zoff;
    int*    lists  = (int*)(ws + off);    off += (size_t)3 * BATCH * 4;

    hipMemsetAsync(ws + zoff, 0, zbytes, stream);

    gemm_fp32<0><<<6144, 256, 0, stream>>>(x, W1, b1, h,
                                           nullptr, nullptr, nullptr, nullptr, KIN, KIN);
    bnstats<<<256, 256, 0, stream>>>(h, s1, s2);
    bnfinal<<<3, 256, 0, stream>>>(s1, s2, gamma, beta, scale, shift);
    gemm_fp32<1><<<6144, 256, 0, stream>>>(h, Wd1, bd1, nullptr,
                                           scale, shift, Wd2, domacc, HD, HD);
    domfinal<<<BATCH / 256, 256, 0, stream>>>(domacc, bd2, outdom, cnt, lists);
    dim3 eg(BATCH / 32, 3);
    expert_kernel<<<eg, 256, 0, stream>>>(h, scale, shift, cnt, lists,
                                          Wa, ba, Wb, bb, outs);
}

// Round 2
// 1680.124 us; speedup vs baseline: 1.5962x; 1.5962x over previous
//
#include <hip/hip_runtime.h>
#include <math.h>

#define BATCH 65536
#define KIN   784
#define HD    768

typedef float f32x4 __attribute__((ext_vector_type(4)));
typedef short s16x8 __attribute__((ext_vector_type(8)));
typedef short s16x4 __attribute__((ext_vector_type(4)));

__device__ __forceinline__ float frelu(float x){ return x > 0.f ? x : 0.f; }

// bf16 RTNE from fp32 (values are finite/sane here; no NaN handling needed)
__device__ __forceinline__ unsigned short f2bf(float v){
    unsigned int u = __builtin_bit_cast(unsigned int, v);
    u += 0x7FFFu + ((u >> 16) & 1u);
    return (unsigned short)(u >> 16);
}
__device__ __forceinline__ float bf2f(unsigned short s){
    unsigned int u = ((unsigned int)s) << 16;
    return __builtin_bit_cast(float, u);
}

// ---------------------------------------------------------------------------
// Split+transpose W[K][N] fp32 -> WhT/WlT [N][KP] bf16 (zero-padded K..KP)
// ---------------------------------------------------------------------------
__global__ __launch_bounds__(256)
void split_wT(const float* __restrict__ W, unsigned short* __restrict__ WhT,
              unsigned short* __restrict__ WlT, int K, int N, int KP)
{
    int idx = blockIdx.x * 256 + threadIdx.x;
    if (idx >= N * KP) return;
    int n = idx / KP, k = idx - n * KP;
    float v = (k < K) ? W[(size_t)k * N + n] : 0.f;
    unsigned short h = f2bf(v);
    WhT[idx] = h;
    WlT[idx] = f2bf(v - bf2f(h));
}

// ---------------------------------------------------------------------------
// Split-bf16 MFMA GEMM: C[M,N] = A[M,K] @ B[K,N], B given pre-split/transposed.
// A is fp32, split to hi/lo bf16 during LDS staging (reg-staged).
// 4 cross-products (hi/lo x hi/lo) accumulated in one fp32 MFMA accumulator
// => ~2^-18 relative error (fp32-class).
// MODE 0: GEMM1 (A=x, K=784 padded to 800), epilogue C = acc + bias -> h.
// MODE 1: GEMM2 (A=h with fused BN+ReLU), epilogue: a=relu(acc+bd1),
//         domacc[row][d] += sum_n a*Wd2[n][d] (shfl-reduced, fp64 atomics).
// Tile 128x128, BK=32, 256 thr (4 waves, 2x2), per-wave 4x4 16x16 frags.
// LDS 32KB single-buffer; slot-XOR swizzle on both write and read sides.
// ---------------------------------------------------------------------------
template<int MODE>
__global__ __launch_bounds__(256, 2)
void gemm_split(const float* __restrict__ A,
                const unsigned short* __restrict__ BhT,
                const unsigned short* __restrict__ BlT,
                const float* __restrict__ bias,
                float* __restrict__ C,
                const float* __restrict__ scale, const float* __restrict__ shift,
                const float* __restrict__ Wd2, double* __restrict__ domacc,
                int K, int KP, int NT, int ldA)
{
    __shared__ __align__(16) char sm[32768];
    const int AH = 0, AL = 8192, BH = 16384, BL = 24576;

    int bid = blockIdx.x;
    int wg = (bid & 7) * 384 + (bid >> 3);      // XCD-contiguous remap (3072%8==0)
    int mb = wg / 6, nb = wg - mb * 6;
    int m0 = mb << 7, n0 = nb << 7;

    int tid = threadIdx.x;
    int lane = tid & 63, wid = tid >> 6;
    int wr = wid >> 1, wc = wid & 1;
    int l15 = lane & 15, l4 = lane >> 4;

    // fragment LDS byte offsets (swizzled): row*64 + ((l4 ^ (row>>2))&3)*16
    int aoff[4], boff[4];
    #pragma unroll
    for (int f = 0; f < 4; f++) {
        int ra = wr * 64 + f * 16 + l15;
        aoff[f] = ra * 64 + (((l4 ^ (ra >> 2)) & 3) << 4);
        int rb = wc * 64 + f * 16 + l15;
        boff[f] = rb * 64 + (((l4 ^ (rb >> 2)) & 3) << 4);
    }

    // staging decompositions
    int ac_r[4], ac_s[4];
    #pragma unroll
    for (int q = 0; q < 4; q++) { int c = q * 256 + tid; ac_r[q] = c >> 3; ac_s[q] = c & 7; }
    int bc_r[2], bc_s[2];
    #pragma unroll
    for (int q = 0; q < 2; q++) { int c = q * 256 + tid; bc_r[q] = c >> 2; bc_s[q] = c & 3; }

    f32x4 acc[4][4];
    #pragma unroll
    for (int i = 0; i < 4; i++)
        #pragma unroll
        for (int j = 0; j < 4; j++) acc[i][j] = (f32x4){0.f, 0.f, 0.f, 0.f};

    float4 av[4];
    s16x8 bvh[2], bvl[2];

    auto loadT = [&](int t) {
        #pragma unroll
        for (int q = 0; q < 4; q++) {
            int kk = t * 32 + ac_s[q] * 4;
            float4 v = make_float4(0.f, 0.f, 0.f, 0.f);
            if (kk < K) v = *(const float4*)(A + (size_t)(m0 + ac_r[q]) * ldA + kk);
            if (MODE == 1) {
                float4 sc = *(const float4*)(scale + kk);
                float4 sh = *(const float4*)(shift + kk);
                v.x = frelu(v.x * sc.x + sh.x); v.y = frelu(v.y * sc.y + sh.y);
                v.z = frelu(v.z * sc.z + sh.z); v.w = frelu(v.w * sc.w + sh.w);
            }
            av[q] = v;
        }
        #pragma unroll
        for (int q = 0; q < 2; q++) {
            size_t go = (size_t)(n0 + bc_r[q]) * KP + t * 32 + bc_s[q] * 8;
            bvh[q] = *(const s16x8*)(BhT + go);
            bvl[q] = *(const s16x8*)(BlT + go);
        }
    };

    auto writeT = [&]() {
        #pragma unroll
        for (int q = 0; q < 4; q++) {
            int r = ac_r[q], s = ac_s[q];
            float4 v = av[q];
            s16x4 hv, lv;
            unsigned short h;
            h = f2bf(v.x); hv[0] = (short)h; lv[0] = (short)f2bf(v.x - bf2f(h));
            h = f2bf(v.y); hv[1] = (short)h; lv[1] = (short)f2bf(v.y - bf2f(h));
            h = f2bf(v.z); hv[2] = (short)h; lv[2] = (short)f2bf(v.z - bf2f(h));
            h = f2bf(v.w); hv[3] = (short)h; lv[3] = (short)f2bf(v.w - bf2f(h));
            int addr = r * 64 + (((((s >> 1) ^ (r >> 2))) & 3) << 4) + ((s & 1) << 3);
            *(s16x4*)(sm + AH + addr) = hv;
            *(s16x4*)(sm + AL + addr) = lv;
        }
        #pragma unroll
        for (int q = 0; q < 2; q++) {
            int r = bc_r[q], s = bc_s[q];
            int addr = r * 64 + (((s ^ (r >> 2)) & 3) << 4);
            *(s16x8*)(sm + BH + addr) = bvh[q];
            *(s16x8*)(sm + BL + addr) = bvl[q];
        }
    };

    loadT(0);
    for (int t = 0; t < NT; t++) {
        __syncthreads();            // prev-tile readers done
        writeT();
        __syncthreads();            // tile visible
        if (t + 1 < NT) loadT(t + 1);   // prefetch into regs; consumed next iter
        s16x8 fah[4], fal[4], fbh[4], fbl[4];
        #pragma unroll
        for (int f = 0; f < 4; f++) {
            fah[f] = *(const s16x8*)(sm + AH + aoff[f]);
            fal[f] = *(const s16x8*)(sm + AL + aoff[f]);
            fbh[f] = *(const s16x8*)(sm + BH + boff[f]);
            fbl[f] = *(const s16x8*)(sm + BL + boff[f]);
        }
        #pragma unroll
        for (int i = 0; i < 4; i++)
            #pragma unroll
            for (int j = 0; j < 4; j++) {
                acc[i][j] = __builtin_amdgcn_mfma_f32_16x16x32_bf16(fal[i], fbl[j], acc[i][j], 0, 0, 0);
                acc[i][j] = __builtin_amdgcn_mfma_f32_16x16x32_bf16(fah[i], fbl[j], acc[i][j], 0, 0, 0);
                acc[i][j] = __builtin_amdgcn_mfma_f32_16x16x32_bf16(fal[i], fbh[j], acc[i][j], 0, 0, 0);
                acc[i][j] = __builtin_amdgcn_mfma_f32_16x16x32_bf16(fah[i], fbh[j], acc[i][j], 0, 0, 0);
            }
    }

    if (MODE == 0) {
        float bc[4];
        #pragma unroll
        for (int f = 0; f < 4; f++) bc[f] = bias[n0 + wc * 64 + f * 16 + l15];
        #pragma unroll
        for (int i = 0; i < 4; i++) {
            int rowb = m0 + wr * 64 + i * 16 + l4 * 4;
            #pragma unroll
            for (int j2 = 0; j2 < 4; j2++) {
                float* crow = C + (size_t)(rowb + j2) * HD + n0 + wc * 64 + l15;
                #pragma unroll
                for (int f = 0; f < 4; f++) crow[f * 16] = acc[i][f][j2] + bc[f];
            }
        }
    } else {
        float bc[4], w2[4][3];
        #pragma unroll
        for (int f = 0; f < 4; f++) {
            int col = n0 + wc * 64 + f * 16 + l15;
            bc[f] = bias[col];
            w2[f][0] = Wd2[col * 3 + 0]; w2[f][1] = Wd2[col * 3 + 1]; w2[f][2] = Wd2[col * 3 + 2];
        }
        float s0[16], s1[16], s2[16];
        #pragma unroll
        for (int i = 0; i < 16; i++) { s0[i] = 0.f; s1[i] = 0.f; s2[i] = 0.f; }
        #pragma unroll
        for (int i = 0; i < 4; i++)
            #pragma unroll
            for (int j2 = 0; j2 < 4; j2++) {
                int idx = i * 4 + j2;
                #pragma unroll
                for (int f = 0; f < 4; f++) {
                    float v = frelu(acc[i][f][j2] + bc[f]);
                    s0[idx] += v * w2[f][0];
                    s1[idx] += v * w2[f][1];
                    s2[idx] += v * w2[f][2];
                }
            }
        #pragma unroll
        for (int m = 1; m < 16; m <<= 1) {
            #pragma unroll
            for (int i = 0; i < 16; i++) {
                s0[i] += __shfl_xor(s0[i], m, 64);
                s1[i] += __shfl_xor(s1[i], m, 64);
                s2[i] += __shfl_xor(s2[i], m, 64);
            }
        }
        if (l15 == 0) {
            #pragma unroll
            for (int i = 0; i < 16; i++) {
                int row = m0 + wr * 64 + (i >> 2) * 16 + l4 * 4 + (i & 3);
                atomicAdd(&domacc[(size_t)row * 3 + 0], (double)s0[i]);
                atomicAdd(&domacc[(size_t)row * 3 + 1], (double)s1[i]);
                atomicAdd(&domacc[(size_t)row * 3 + 2], (double)s2[i]);
            }
        }
    }
}

// ---- BN statistics: deterministic two-stage fp64 column reduction ----------
__global__ __launch_bounds__(256)
void bnstats(const float* __restrict__ h, double* __restrict__ s1, double* __restrict__ s2)
{
    int b = blockIdx.x, t = threadIdx.x;
    const float* base = h + (size_t)b * 256 * HD;
    double a0 = 0, a1 = 0, a2 = 0, q0 = 0, q1 = 0, q2 = 0;
    for (int r = 0; r < 256; r++) {
        const float* row = base + (size_t)r * HD;
        float v0 = row[t], v1 = row[t + 256], v2 = row[t + 512];
        a0 += v0; a1 += v1; a2 += v2;
        q0 += (double)v0 * (double)v0;
        q1 += (double)v1 * (double)v1;
        q2 += (double)v2 * (double)v2;
    }
    s1[(size_t)b * HD + t] = a0; s1[(size_t)b * HD + t + 256] = a1; s1[(size_t)b * HD + t + 512] = a2;
    s2[(size_t)b * HD + t] = q0; s2[(size_t)b * HD + t + 256] = q1; s2[(size_t)b * HD + t + 512] = q2;
}

__global__ void bnfinal(const double* __restrict__ s1, const double* __restrict__ s2,
                        const float* __restrict__ gamma, const float* __restrict__ beta,
                        float* __restrict__ scale, float* __restrict__ shift)
{
    int c = blockIdx.x * 256 + threadIdx.x;
    if (c >= HD) return;
    double S = 0, Q = 0;
    for (int b = 0; b < 256; b++) { S += s1[(size_t)b * HD + c]; Q += s2[(size_t)b * HD + c]; }
    double mu  = S * (1.0 / 65536.0);
    double var = Q * (1.0 / 65536.0) - mu * mu;
    double inv = 1.0 / sqrt(var + 1e-5);
    double sc  = inv * (double)gamma[c];
    double sh  = (double)beta[c] - mu * sc;
    scale[c] = (float)sc;
    shift[c] = (float)sh;
}

// ---- dom_out finalize pass A: write outdom, flag borderline rows -----------
__global__ __launch_bounds__(256)
void domfinal_a(const double* __restrict__ domacc, const float* __restrict__ bd2,
                float* __restrict__ outdom, int* __restrict__ fixmeta, int* __restrict__ fixlist)
{
    int r = blockIdx.x * 256 + threadIdx.x;
    double v0 = domacc[(size_t)r * 3 + 0] + (double)bd2[0];
    double v1 = domacc[(size_t)r * 3 + 1] + (double)bd2[1];
    double v2 = domacc[(size_t)r * 3 + 2] + (double)bd2[2];
    outdom[(size_t)r * 3 + 0] = (float)v0;
    outdom[(size_t)r * 3 + 1] = (float)v1;
    outdom[(size_t)r * 3 + 2] = (float)v2;
    double mx01 = v0 > v1 ? v0 : v1, mn01 = v0 > v1 ? v1 : v0;
    double best = mx01 > v2 ? mx01 : v2;
    double m2   = mx01 > v2 ? (mn01 > v2 ? mn01 : v2) : mx01;
    if (best - m2 < 1e-3) {
        int p = atomicAdd(fixmeta, 1);
        fixlist[p] = r;
    }
}

// ---- exact fp32 recompute of dom_out for borderline rows (16 rows/block) ---
__global__ __launch_bounds__(256)
void fixrow(const int* __restrict__ fixmeta, const int* __restrict__ fixlist,
            const float* __restrict__ hbuf, const float* __restrict__ scale,
            const float* __restrict__ shift, const float* __restrict__ Wd1,
            const float* __restrict__ bd1, const float* __restrict__ Wd2,
            const float* __restrict__ bd2, float* __restrict__ outdom)
{
    int nfix = fixmeta[0];
    __shared__ float feat[16][HD];
    __shared__ float red[4][3];
    int tid = threadIdx.x;
    for (int base = blockIdx.x * 16; base < nfix; base += gridDim.x * 16) {
        int nr = nfix - base; if (nr > 16) nr = 16;
        __syncthreads();
        for (int i = tid; i < nr * HD; i += 256) {
            int rr = i / HD, c = i - rr * HD;
            int row = fixlist[base + rr];
            feat[rr][c] = frelu(hbuf[(size_t)row * HD + c] * scale[c] + shift[c]);
        }
        __syncthreads();
        int n0 = tid * 3;
        float acc[16][3];
        #pragma unroll
        for (int rr = 0; rr < 16; rr++) { acc[rr][0] = 0.f; acc[rr][1] = 0.f; acc[rr][2] = 0.f; }
        for (int k = 0; k < HD; k++) {
            float w0 = Wd1[(size_t)k * HD + n0];
            float w1 = Wd1[(size_t)k * HD + n0 + 1];
            float w2 = Wd1[(size_t)k * HD + n0 + 2];
            #pragma unroll
            for (int rr = 0; rr < 16; rr++) {
                float fv = feat[rr][k];
                acc[rr][0] += fv * w0; acc[rr][1] += fv * w1; acc[rr][2] += fv * w2;
            }
        }
        float b0 = bd1[n0], b1 = bd1[n0 + 1], b2 = bd1[n0 + 2];
        float wa[3][3];
        #pragma unroll
        for (int i = 0; i < 3; i++)
            #pragma unroll
            for (int d = 0; d < 3; d++) wa[i][d] = Wd2[(n0 + i) * 3 + d];
        #pragma unroll
        for (int rr = 0; rr < 16; rr++) {
            if (rr >= nr) break;
            float h0 = frelu(acc[rr][0] + b0);
            float h1 = frelu(acc[rr][1] + b1);
            float h2 = frelu(acc[rr][2] + b2);
            float y0 = h0 * wa[0][0] + h1 * wa[1][0] + h2 * wa[2][0];
            float y1 = h0 * wa[0][1] + h1 * wa[1][1] + h2 * wa[2][1];
            float y2 = h0 * wa[0][2] + h1 * wa[1][2] + h2 * wa[2][2];
            #pragma unroll
            for (int m = 1; m < 64; m <<= 1) {
                y0 += __shfl_xor(y0, m, 64);
                y1 += __shfl_xor(y1, m, 64);
                y2 += __shfl_xor(y2, m, 64);
            }
            if ((tid & 63) == 0) { red[tid >> 6][0] = y0; red[tid >> 6][1] = y1; red[tid >> 6][2] = y2; }
            __syncthreads();
            if (tid == 0) {
                int row = fixlist[base + rr];
                double v0 = (double)red[0][0] + red[1][0] + red[2][0] + red[3][0] + (double)bd2[0];
                double v1 = (double)red[0][1] + red[1][1] + red[2][1] + red[3][1] + (double)bd2[1];
                double v2 = (double)red[0][2] + red[1][2] + red[2][2] + red[3][2] + (double)bd2[2];
                outdom[(size_t)row * 3 + 0] = (float)v0;
                outdom[(size_t)row * 3 + 1] = (float)v1;
                outdom[(size_t)row * 3 + 2] = (float)v2;
            }
            __syncthreads();
        }
    }
}

// ---- pass B: argmax (first-index tie-break) + bucket by domain -------------
__global__ __launch_bounds__(256)
void domfinal_b(const float* __restrict__ outdom, int* __restrict__ cnt, int* __restrict__ lists)
{
    int r = blockIdx.x * 256 + threadIdx.x;
    float v0 = outdom[(size_t)r * 3 + 0];
    float v1 = outdom[(size_t)r * 3 + 1];
    float v2 = outdom[(size_t)r * 3 + 2];
    int p = 0; float best = v0;
    if (v1 > best) { best = v1; p = 1; }
    if (v2 > best) { best = v2; p = 2; }
    int pos = atomicAdd(&cnt[p], 1);
    lists[(size_t)p * BATCH + pos] = r;
}

// ---- expert MLP: 32 same-domain rows per block, Wa staged through LDS ------
__global__ __launch_bounds__(256)
void expert_kernel(const float* __restrict__ h, const float* __restrict__ scale, const float* __restrict__ shift,
                   const int* __restrict__ cnt, const int* __restrict__ lists,
                   const float* __restrict__ Wa, const float* __restrict__ ba,
                   const float* __restrict__ Wb, const float* __restrict__ bb,
                   float* __restrict__ outs)
{
    int d = blockIdx.y;
    int start = blockIdx.x * 32;
    int count = cnt[d];
    if (start >= count) return;
    int nrows = count - start; if (nrows > 32) nrows = 32;

    __shared__ int   rowidx[32];
    __shared__ float fs[32][68];
    __shared__ float wsa[64][64];
    __shared__ float hid[32][64];

    int tid = threadIdx.x;
    if (tid < 32) {
        int i = tid < nrows ? tid : (nrows - 1);
        rowidx[tid] = lists[(size_t)d * BATCH + start + i];
    }
    __syncthreads();

    int rr = tid >> 3;
    int g  = tid & 7;
    int fcol = g << 3;

    float hacc[8] = {0, 0, 0, 0, 0, 0, 0, 0};

    for (int k0 = 0; k0 < HD; k0 += 64) {
        {
            int row = rowidx[rr];
            const float* hp  = h + (size_t)row * HD + k0 + fcol;
            const float* scp = scale + k0 + fcol;
            const float* shp = shift + k0 + fcol;
            float4 v0 = *(const float4*)hp;
            float4 v1 = *(const float4*)(hp + 4);
            fs[rr][fcol + 0] = frelu(v0.x * scp[0] + shp[0]);
            fs[rr][fcol + 1] = frelu(v0.y * scp[1] + shp[1]);
            fs[rr][fcol + 2] = frelu(v0.z * scp[2] + shp[2]);
            fs[rr][fcol + 3] = frelu(v0.w * scp[3] + shp[3]);
            fs[rr][fcol + 4] = frelu(v1.x * scp[4] + shp[4]);
            fs[rr][fcol + 5] = frelu(v1.y * scp[5] + shp[5]);
            fs[rr][fcol + 6] = frelu(v1.z * scp[6] + shp[6]);
            fs[rr][fcol + 7] = frelu(v1.w * scp[7] + shp[7]);
        }
        #pragma unroll
        for (int rep = 0; rep < 4; rep++) {
            int idx = rep * 256 + tid;
            int kk = idx >> 4;
            int f4 = (idx & 15) << 2;
            *(float4*)&wsa[kk][f4] = *(const float4*)(Wa + ((size_t)d * HD + k0 + kk) * 64 + f4);
        }
        __syncthreads();
        #pragma unroll 8
        for (int kk = 0; kk < 64; kk++) {
            float fv = fs[rr][kk];
            const float* wrow = &wsa[kk][g << 3];
            float4 w0 = *(const float4*)wrow;
            float4 w1 = *(const float4*)(wrow + 4);
            hacc[0] += fv * w0.x; hacc[1] += fv * w0.y; hacc[2] += fv * w0.z; hacc[3] += fv * w0.w;
            hacc[4] += fv * w1.x; hacc[5] += fv * w1.y; hacc[6] += fv * w1.z; hacc[7] += fv * w1.w;
        }
        __syncthreads();
    }

    #pragma unroll
    for (int j = 0; j < 8; j++) {
        float v = hacc[j] + ba[d * 64 + fcol + j];
        hid[rr][fcol + j] = frelu(v);
    }
    __syncthreads();

    for (int o = tid; o < 320; o += 256) {
        int r2 = o / 10, c = o - r2 * 10;
        if (r2 < nrows) {
            float s = 0.f;
            #pragma unroll 16
            for (int l = 0; l < 64; l++) s += hid[r2][l] * Wb[((size_t)d * 64 + l) * 10 + c];
            outs[(size_t)rowidx[r2] * 10 + c] = s + bb[d * 10 + c];
        }
    }
}

// ---------------------------------------------------------------------------
extern "C" void kernel_launch(void* const* d_in, const int* in_sizes, int n_in,
                              void* d_out, int out_size, void* d_ws, size_t ws_size,
                              hipStream_t stream)
{
    const float* x     = (const float*)d_in[0];
    const float* W1    = (const float*)d_in[1];
    const float* b1    = (const float*)d_in[2];
    const float* gamma = (const float*)d_in[3];
    const float* beta  = (const float*)d_in[4];
    const float* Wd1   = (const float*)d_in[5];
    const float* bd1   = (const float*)d_in[6];
    const float* Wd2   = (const float*)d_in[7];
    const float* bd2   = (const float*)d_in[8];
    const float* Wa    = (const float*)d_in[9];
    const float* ba    = (const float*)d_in[10];
    const float* Wb    = (const float*)d_in[11];
    const float* bb    = (const float*)d_in[12];

    float* out    = (float*)d_out;
    float* outs   = out;
    float* outdom = out + (size_t)BATCH * 10;

    char* ws = (char*)d_ws;
    size_t off = 0;
    float*  h      = (float*)(ws + off);            off += (size_t)BATCH * HD * 4;
    unsigned short* W1hT  = (unsigned short*)(ws + off); off += (size_t)HD * 800 * 2;
    unsigned short* W1lT  = (unsigned short*)(ws + off); off += (size_t)HD * 800 * 2;
    unsigned short* Wd1hT = (unsigned short*)(ws + off); off += (size_t)HD * HD * 2;
    unsigned short* Wd1lT = (unsigned short*)(ws + off); off += (size_t)HD * HD * 2;
    double* s1     = (double*)(ws + off);           off += (size_t)256 * HD * 8;
    double* s2     = (double*)(ws + off);           off += (size_t)256 * HD * 8;
    float*  scale  = (float*)(ws + off);            off += HD * 4;
    float*  shift  = (float*)(ws + off);            off += HD * 4;
    size_t zoff = off;
    double* domacc = (double*)(ws + off);           off += (size_t)BATCH * 3 * 8;
    int*    cnt    = (int*)(ws + off);              off += 64;
    int*    fixmeta= (int*)(ws + off);              off += 64;
    size_t zbytes = off - zoff;
    int*    lists  = (int*)(ws + off);              off += (size_t)3 * BATCH * 4;
    int*    fixlist= (int*)(ws + off);              off += (size_t)BATCH * 4;

    hipMemsetAsync(ws + zoff, 0, zbytes, stream);

    split_wT<<<(HD * 800) / 256, 256, 0, stream>>>(W1, W1hT, W1lT, KIN, HD, 800);
    split_wT<<<(HD * HD) / 256, 256, 0, stream>>>(Wd1, Wd1hT, Wd1lT, HD, HD, HD);

    gemm_split<0><<<3072, 256, 0, stream>>>(x, W1hT, W1lT, b1, h,
                                            nullptr, nullptr, nullptr, nullptr,
                                            KIN, 800, 25, KIN);
    bnstats<<<256, 256, 0, stream>>>(h, s1, s2);
    bnfinal<<<3, 256, 0, stream>>>(s1, s2, gamma, beta, scale, shift);
    gemm_split<1><<<3072, 256, 0, stream>>>(h, Wd1hT, Wd1lT, bd1, nullptr,
                                            scale, shift, Wd2, domacc,
                                            HD, HD, 24, HD);
    domfinal_a<<<BATCH / 256, 256, 0, stream>>>(domacc, bd2, outdom, fixmeta, fixlist);
    fixrow<<<16, 256, 0, stream>>>(fixmeta, fixlist, h, scale, shift, Wd1, bd1, Wd2, bd2, outdom);
    domfinal_b<<<BATCH / 256, 256, 0, stream>>>(outdom, cnt, lists);
    dim3 eg(BATCH / 32, 3);
    expert_kernel<<<eg, 256, 0, stream>>>(h, scale, shift, cnt, lists,
                                          Wa, ba, Wb, bb, outs);
}

// Round 3
// 1029.409 us; speedup vs baseline: 2.6052x; 1.6321x over previous
//
#include <hip/hip_runtime.h>
#include <math.h>

#define BATCH 65536
#define KIN   784
#define HD    768

typedef float f32x4 __attribute__((ext_vector_type(4)));
typedef short s16x8 __attribute__((ext_vector_type(8)));
typedef short s16x4 __attribute__((ext_vector_type(4)));

__device__ __forceinline__ float frelu(float x){ return x > 0.f ? x : 0.f; }

// bf16 RTNE from fp32 (values are finite/sane here; no NaN handling needed)
__device__ __forceinline__ unsigned short f2bf(float v){
    unsigned int u = __builtin_bit_cast(unsigned int, v);
    u += 0x7FFFu + ((u >> 16) & 1u);
    return (unsigned short)(u >> 16);
}
__device__ __forceinline__ float bf2f(unsigned short s){
    unsigned int u = ((unsigned int)s) << 16;
    return __builtin_bit_cast(float, u);
}

// ---------------------------------------------------------------------------
// Split+transpose W[K][N] fp32 -> WhT/WlT [N][KP] bf16 (zero-padded K..KP)
// ---------------------------------------------------------------------------
__global__ __launch_bounds__(256)
void split_wT(const float* __restrict__ W, unsigned short* __restrict__ WhT,
              unsigned short* __restrict__ WlT, int K, int N, int KP)
{
    int idx = blockIdx.x * 256 + threadIdx.x;
    if (idx >= N * KP) return;
    int n = idx / KP, k = idx - n * KP;
    float v = (k < K) ? W[(size_t)k * N + n] : 0.f;
    unsigned short h = f2bf(v);
    WhT[idx] = h;
    WlT[idx] = f2bf(v - bf2f(h));
}

// ---------------------------------------------------------------------------
// Split-bf16 MFMA GEMM: C[M,N] = A[M,K] @ B[K,N], B pre-split/transposed.
// 3 cross-products (hi*hi + hi*lo + lo*hi) in one fp32 accumulator:
// dropped lo*lo term contributes ~2^-18 rel — fp32-class accuracy.
// MODE 0: GEMM1 (A=x), epilogue C = acc + bias -> h.
// MODE 1: GEMM2 (A=h with fused BN+ReLU), epilogue: a=relu(acc+bd1),
//         domacc[row][d] += sum_n a*Wd2[n][d] (shfl-reduced, fp64 atomics).
// Tile 128x128, BK=32, 256 thr (4 waves 2x2), per-wave 4x4 16x16 frags.
// LDS 32KB single-buffer; slot-XOR swizzle on write AND read sides.
// ---------------------------------------------------------------------------
template<int MODE>
__global__ __launch_bounds__(256, 2)
void gemm_split(const float* __restrict__ A,
                const unsigned short* __restrict__ BhT,
                const unsigned short* __restrict__ BlT,
                const float* __restrict__ bias,
                float* __restrict__ C,
                const float* __restrict__ scale, const float* __restrict__ shift,
                const float* __restrict__ Wd2, double* __restrict__ domacc,
                int K, int KP, int NT, int ldA)
{
    __shared__ __align__(16) char sm[32768];
    const int AH = 0, AL = 8192, BH = 16384, BL = 24576;

    int bid = blockIdx.x;
    int wg = (bid & 7) * 384 + (bid >> 3);      // XCD-contiguous remap (3072%8==0)
    int mb = wg / 6, nb = wg - mb * 6;
    int m0 = mb << 7, n0 = nb << 7;

    int tid = threadIdx.x;
    int lane = tid & 63, wid = tid >> 6;
    int wr = wid >> 1, wc = wid & 1;
    int l15 = lane & 15, l4 = lane >> 4;

    // fragment LDS byte offsets (swizzled): row*64 + ((l4 ^ (row>>2))&3)*16
    int aoff[4], boff[4];
    #pragma unroll
    for (int f = 0; f < 4; f++) {
        int ra = wr * 64 + f * 16 + l15;
        aoff[f] = ra * 64 + (((l4 ^ (ra >> 2)) & 3) << 4);
        int rb = wc * 64 + f * 16 + l15;
        boff[f] = rb * 64 + (((l4 ^ (rb >> 2)) & 3) << 4);
    }

    // staging decompositions
    int ac_r[4], ac_s[4];
    #pragma unroll
    for (int q = 0; q < 4; q++) { int c = q * 256 + tid; ac_r[q] = c >> 3; ac_s[q] = c & 7; }
    int bc_r[2], bc_s[2];
    #pragma unroll
    for (int q = 0; q < 2; q++) { int c = q * 256 + tid; bc_r[q] = c >> 2; bc_s[q] = c & 3; }

    f32x4 acc[4][4];
    #pragma unroll
    for (int i = 0; i < 4; i++)
        #pragma unroll
        for (int j = 0; j < 4; j++) acc[i][j] = (f32x4){0.f, 0.f, 0.f, 0.f};

    float4 av[4];
    s16x8 bvh[2], bvl[2];

    auto loadT = [&](int t) {
        #pragma unroll
        for (int q = 0; q < 4; q++) {
            int kk = t * 32 + ac_s[q] * 4;
            float4 v = make_float4(0.f, 0.f, 0.f, 0.f);
            if (kk < K) v = *(const float4*)(A + (size_t)(m0 + ac_r[q]) * ldA + kk);
            if (MODE == 1) {
                float4 sc = *(const float4*)(scale + kk);
                float4 sh = *(const float4*)(shift + kk);
                v.x = frelu(v.x * sc.x + sh.x); v.y = frelu(v.y * sc.y + sh.y);
                v.z = frelu(v.z * sc.z + sh.z); v.w = frelu(v.w * sc.w + sh.w);
            }
            av[q] = v;
        }
        #pragma unroll
        for (int q = 0; q < 2; q++) {
            size_t go = (size_t)(n0 + bc_r[q]) * KP + t * 32 + bc_s[q] * 8;
            bvh[q] = *(const s16x8*)(BhT + go);
            bvl[q] = *(const s16x8*)(BlT + go);
        }
    };

    auto writeT = [&]() {
        #pragma unroll
        for (int q = 0; q < 4; q++) {
            int r = ac_r[q], s = ac_s[q];
            float4 v = av[q];
            s16x4 hv, lv;
            unsigned short h;
            h = f2bf(v.x); hv[0] = (short)h; lv[0] = (short)f2bf(v.x - bf2f(h));
            h = f2bf(v.y); hv[1] = (short)h; lv[1] = (short)f2bf(v.y - bf2f(h));
            h = f2bf(v.z); hv[2] = (short)h; lv[2] = (short)f2bf(v.z - bf2f(h));
            h = f2bf(v.w); hv[3] = (short)h; lv[3] = (short)f2bf(v.w - bf2f(h));
            int addr = r * 64 + (((((s >> 1) ^ (r >> 2))) & 3) << 4) + ((s & 1) << 3);
            *(s16x4*)(sm + AH + addr) = hv;
            *(s16x4*)(sm + AL + addr) = lv;
        }
        #pragma unroll
        for (int q = 0; q < 2; q++) {
            int r = bc_r[q], s = bc_s[q];
            int addr = r * 64 + (((s ^ (r >> 2)) & 3) << 4);
            *(s16x8*)(sm + BH + addr) = bvh[q];
            *(s16x8*)(sm + BL + addr) = bvl[q];
        }
    };

    loadT(0);
    for (int t = 0; t < NT; t++) {
        __syncthreads();            // prev-tile readers done
        writeT();
        __syncthreads();            // tile visible
        if (t + 1 < NT) loadT(t + 1);   // prefetch into regs; consumed next iter
        s16x8 fah[4], fal[4], fbh[4], fbl[4];
        #pragma unroll
        for (int f = 0; f < 4; f++) {
            fah[f] = *(const s16x8*)(sm + AH + aoff[f]);
            fal[f] = *(const s16x8*)(sm + AL + aoff[f]);
            fbh[f] = *(const s16x8*)(sm + BH + boff[f]);
            fbl[f] = *(const s16x8*)(sm + BL + boff[f]);
        }
        #pragma unroll
        for (int i = 0; i < 4; i++)
            #pragma unroll
            for (int j = 0; j < 4; j++) {
                acc[i][j] = __builtin_amdgcn_mfma_f32_16x16x32_bf16(fah[i], fbl[j], acc[i][j], 0, 0, 0);
                acc[i][j] = __builtin_amdgcn_mfma_f32_16x16x32_bf16(fal[i], fbh[j], acc[i][j], 0, 0, 0);
                acc[i][j] = __builtin_amdgcn_mfma_f32_16x16x32_bf16(fah[i], fbh[j], acc[i][j], 0, 0, 0);
            }
    }

    if (MODE == 0) {
        float bc[4];
        #pragma unroll
        for (int f = 0; f < 4; f++) bc[f] = bias[n0 + wc * 64 + f * 16 + l15];
        #pragma unroll
        for (int i = 0; i < 4; i++) {
            int rowb = m0 + wr * 64 + i * 16 + l4 * 4;
            #pragma unroll
            for (int j2 = 0; j2 < 4; j2++) {
                float* crow = C + (size_t)(rowb + j2) * HD + n0 + wc * 64 + l15;
                #pragma unroll
                for (int f = 0; f < 4; f++) crow[f * 16] = acc[i][f][j2] + bc[f];
            }
        }
    } else {
        float bc[4], w2[4][3];
        #pragma unroll
        for (int f = 0; f < 4; f++) {
            int col = n0 + wc * 64 + f * 16 + l15;
            bc[f] = bias[col];
            w2[f][0] = Wd2[col * 3 + 0]; w2[f][1] = Wd2[col * 3 + 1]; w2[f][2] = Wd2[col * 3 + 2];
        }
        float s0[16], s1[16], s2[16];
        #pragma unroll
        for (int i = 0; i < 16; i++) { s0[i] = 0.f; s1[i] = 0.f; s2[i] = 0.f; }
        #pragma unroll
        for (int i = 0; i < 4; i++)
            #pragma unroll
            for (int j2 = 0; j2 < 4; j2++) {
                int idx = i * 4 + j2;
                #pragma unroll
                for (int f = 0; f < 4; f++) {
                    float v = frelu(acc[i][f][j2] + bc[f]);
                    s0[idx] += v * w2[f][0];
                    s1[idx] += v * w2[f][1];
                    s2[idx] += v * w2[f][2];
                }
            }
        #pragma unroll
        for (int m = 1; m < 16; m <<= 1) {
            #pragma unroll
            for (int i = 0; i < 16; i++) {
                s0[i] += __shfl_xor(s0[i], m, 64);
                s1[i] += __shfl_xor(s1[i], m, 64);
                s2[i] += __shfl_xor(s2[i], m, 64);
            }
        }
        if (l15 == 0) {
            #pragma unroll
            for (int i = 0; i < 16; i++) {
                int row = m0 + wr * 64 + (i >> 2) * 16 + l4 * 4 + (i & 3);
                atomicAdd(&domacc[(size_t)row * 3 + 0], (double)s0[i]);
                atomicAdd(&domacc[(size_t)row * 3 + 1], (double)s1[i]);
                atomicAdd(&domacc[(size_t)row * 3 + 2], (double)s2[i]);
            }
        }
    }
}

// ---- BN statistics: deterministic two-stage fp64 column reduction ----------
#define BNB 512
__global__ __launch_bounds__(256)
void bnstats(const float* __restrict__ h, double* __restrict__ s1, double* __restrict__ s2)
{
    int b = blockIdx.x, t = threadIdx.x;
    const float* base = h + (size_t)b * 128 * HD;
    double a0 = 0, a1 = 0, a2 = 0, q0 = 0, q1 = 0, q2 = 0;
    for (int r = 0; r < 128; r++) {
        const float* row = base + (size_t)r * HD;
        float v0 = row[t], v1 = row[t + 256], v2 = row[t + 512];
        a0 += v0; a1 += v1; a2 += v2;
        q0 += (double)v0 * (double)v0;
        q1 += (double)v1 * (double)v1;
        q2 += (double)v2 * (double)v2;
    }
    s1[(size_t)b * HD + t] = a0; s1[(size_t)b * HD + t + 256] = a1; s1[(size_t)b * HD + t + 512] = a2;
    s2[(size_t)b * HD + t] = q0; s2[(size_t)b * HD + t + 256] = q1; s2[(size_t)b * HD + t + 512] = q2;
}

__global__ void bnfinal(const double* __restrict__ s1, const double* __restrict__ s2,
                        const float* __restrict__ gamma, const float* __restrict__ beta,
                        float* __restrict__ scale, float* __restrict__ shift)
{
    int c = blockIdx.x * 256 + threadIdx.x;
    if (c >= HD) return;
    double S = 0, Q = 0;
    for (int b = 0; b < BNB; b++) { S += s1[(size_t)b * HD + c]; Q += s2[(size_t)b * HD + c]; }
    double mu  = S * (1.0 / 65536.0);
    double var = Q * (1.0 / 65536.0) - mu * mu;
    double inv = 1.0 / sqrt(var + 1e-5);
    double sc  = inv * (double)gamma[c];
    double sh  = (double)beta[c] - mu * sc;
    scale[c] = (float)sc;
    shift[c] = (float)sh;
}

// ---- dom_out finalize pass A: write outdom, flag borderline rows -----------
__global__ __launch_bounds__(256)
void domfinal_a(const double* __restrict__ domacc, const float* __restrict__ bd2,
                float* __restrict__ outdom, int* __restrict__ fixmeta, int* __restrict__ fixlist)
{
    int r = blockIdx.x * 256 + threadIdx.x;
    double v0 = domacc[(size_t)r * 3 + 0] + (double)bd2[0];
    double v1 = domacc[(size_t)r * 3 + 1] + (double)bd2[1];
    double v2 = domacc[(size_t)r * 3 + 2] + (double)bd2[2];
    outdom[(size_t)r * 3 + 0] = (float)v0;
    outdom[(size_t)r * 3 + 1] = (float)v1;
    outdom[(size_t)r * 3 + 2] = (float)v2;
    double mx01 = v0 > v1 ? v0 : v1, mn01 = v0 > v1 ? v1 : v0;
    double best = mx01 > v2 ? mx01 : v2;
    double m2   = mx01 > v2 ? (mn01 > v2 ? mn01 : v2) : mx01;
    if (best - m2 < 1e-3) {
        int p = atomicAdd(fixmeta, 1);
        fixlist[p] = r;
    }
}

// ---- exact fp32 recompute of dom_out for borderline rows (16 rows/block) ---
__global__ __launch_bounds__(256)
void fixrow(const int* __restrict__ fixmeta, const int* __restrict__ fixlist,
            const float* __restrict__ hbuf, const float* __restrict__ scale,
            const float* __restrict__ shift, const float* __restrict__ Wd1,
            const float* __restrict__ bd1, const float* __restrict__ Wd2,
            const float* __restrict__ bd2, float* __restrict__ outdom)
{
    int nfix = fixmeta[0];
    __shared__ float feat[16][HD];
    __shared__ float red[4][3];
    int tid = threadIdx.x;
    for (int base = blockIdx.x * 16; base < nfix; base += gridDim.x * 16) {
        int nr = nfix - base; if (nr > 16) nr = 16;
        __syncthreads();
        for (int i = tid; i < nr * HD; i += 256) {
            int rr = i / HD, c = i - rr * HD;
            int row = fixlist[base + rr];
            feat[rr][c] = frelu(hbuf[(size_t)row * HD + c] * scale[c] + shift[c]);
        }
        __syncthreads();
        int n0 = tid * 3;
        float acc[16][3];
        #pragma unroll
        for (int rr = 0; rr < 16; rr++) { acc[rr][0] = 0.f; acc[rr][1] = 0.f; acc[rr][2] = 0.f; }
        for (int k = 0; k < HD; k++) {
            float w0 = Wd1[(size_t)k * HD + n0];
            float w1 = Wd1[(size_t)k * HD + n0 + 1];
            float w2 = Wd1[(size_t)k * HD + n0 + 2];
            #pragma unroll
            for (int rr = 0; rr < 16; rr++) {
                float fv = feat[rr][k];
                acc[rr][0] += fv * w0; acc[rr][1] += fv * w1; acc[rr][2] += fv * w2;
            }
        }
        float b0 = bd1[n0], b1 = bd1[n0 + 1], b2 = bd1[n0 + 2];
        float wa[3][3];
        #pragma unroll
        for (int i = 0; i < 3; i++)
            #pragma unroll
            for (int d = 0; d < 3; d++) wa[i][d] = Wd2[(n0 + i) * 3 + d];
        #pragma unroll
        for (int rr = 0; rr < 16; rr++) {
            if (rr >= nr) break;
            float h0 = frelu(acc[rr][0] + b0);
            float h1 = frelu(acc[rr][1] + b1);
            float h2 = frelu(acc[rr][2] + b2);
            float y0 = h0 * wa[0][0] + h1 * wa[1][0] + h2 * wa[2][0];
            float y1 = h0 * wa[0][1] + h1 * wa[1][1] + h2 * wa[2][1];
            float y2 = h0 * wa[0][2] + h1 * wa[1][2] + h2 * wa[2][2];
            #pragma unroll
            for (int m = 1; m < 64; m <<= 1) {
                y0 += __shfl_xor(y0, m, 64);
                y1 += __shfl_xor(y1, m, 64);
                y2 += __shfl_xor(y2, m, 64);
            }
            if ((tid & 63) == 0) { red[tid >> 6][0] = y0; red[tid >> 6][1] = y1; red[tid >> 6][2] = y2; }
            __syncthreads();
            if (tid == 0) {
                int row = fixlist[base + rr];
                double v0 = (double)red[0][0] + red[1][0] + red[2][0] + red[3][0] + (double)bd2[0];
                double v1 = (double)red[0][1] + red[1][1] + red[2][1] + red[3][1] + (double)bd2[1];
                double v2 = (double)red[0][2] + red[1][2] + red[2][2] + red[3][2] + (double)bd2[2];
                outdom[(size_t)row * 3 + 0] = (float)v0;
                outdom[(size_t)row * 3 + 1] = (float)v1;
                outdom[(size_t)row * 3 + 2] = (float)v2;
            }
            __syncthreads();
        }
    }
}

// ---- pass B: argmax + bucket. Block-aggregated: 3 global atomics per block -
__global__ __launch_bounds__(256)
void domfinal_b(const float* __restrict__ outdom, int* __restrict__ cnt, int* __restrict__ lists)
{
    __shared__ int lcnt[3], base[3];
    int tid = threadIdx.x;
    if (tid < 3) lcnt[tid] = 0;
    __syncthreads();
    int r = blockIdx.x * 256 + tid;
    float v0 = outdom[(size_t)r * 3 + 0];
    float v1 = outdom[(size_t)r * 3 + 1];
    float v2 = outdom[(size_t)r * 3 + 2];
    int p = 0; float best = v0;
    if (v1 > best) { best = v1; p = 1; }
    if (v2 > best) { best = v2; p = 2; }
    int lpos = atomicAdd(&lcnt[p], 1);           // LDS atomic, cheap
    __syncthreads();
    if (tid < 3) base[tid] = atomicAdd(&cnt[tid], lcnt[tid]);  // 3 global/block
    __syncthreads();
    lists[(size_t)p * BATCH + base[p] + lpos] = r;
}

// ---- expert MLP: 32 same-domain rows per block, Wa staged through LDS ------
__global__ __launch_bounds__(256)
void expert_kernel(const float* __restrict__ h, const float* __restrict__ scale, const float* __restrict__ shift,
                   const int* __restrict__ cnt, const int* __restrict__ lists,
                   const float* __restrict__ Wa, const float* __restrict__ ba,
                   const float* __restrict__ Wb, const float* __restrict__ bb,
                   float* __restrict__ outs)
{
    int d = blockIdx.y;
    int start = blockIdx.x * 32;
    int count = cnt[d];
    if (start >= count) return;
    int nrows = count - start; if (nrows > 32) nrows = 32;

    __shared__ int   rowidx[32];
    __shared__ float fs[32][68];
    __shared__ float wsa[64][64];
    __shared__ float hid[32][64];

    int tid = threadIdx.x;
    if (tid < 32) {
        int i = tid < nrows ? tid : (nrows - 1);
        rowidx[tid] = lists[(size_t)d * BATCH + start + i];
    }
    __syncthreads();

    int rr = tid >> 3;
    int g  = tid & 7;
    int fcol = g << 3;

    float hacc[8] = {0, 0, 0, 0, 0, 0, 0, 0};

    for (int k0 = 0; k0 < HD; k0 += 64) {
        {
            int row = rowidx[rr];
            const float* hp  = h + (size_t)row * HD + k0 + fcol;
            const float* scp = scale + k0 + fcol;
            const float* shp = shift + k0 + fcol;
            float4 v0 = *(const float4*)hp;
            float4 v1 = *(const float4*)(hp + 4);
            fs[rr][fcol + 0] = frelu(v0.x * scp[0] + shp[0]);
            fs[rr][fcol + 1] = frelu(v0.y * scp[1] + shp[1]);
            fs[rr][fcol + 2] = frelu(v0.z * scp[2] + shp[2]);
            fs[rr][fcol + 3] = frelu(v0.w * scp[3] + shp[3]);
            fs[rr][fcol + 4] = frelu(v1.x * scp[4] + shp[4]);
            fs[rr][fcol + 5] = frelu(v1.y * scp[5] + shp[5]);
            fs[rr][fcol + 6] = frelu(v1.z * scp[6] + shp[6]);
            fs[rr][fcol + 7] = frelu(v1.w * scp[7] + shp[7]);
        }
        #pragma unroll
        for (int rep = 0; rep < 4; rep++) {
            int idx = rep * 256 + tid;
            int kk = idx >> 4;
            int f4 = (idx & 15) << 2;
            *(float4*)&wsa[kk][f4] = *(const float4*)(Wa + ((size_t)d * HD + k0 + kk) * 64 + f4);
        }
        __syncthreads();
        #pragma unroll 8
        for (int kk = 0; kk < 64; kk++) {
            float fv = fs[rr][kk];
            const float* wrow = &wsa[kk][g << 3];
            float4 w0 = *(const float4*)wrow;
            float4 w1 = *(const float4*)(wrow + 4);
            hacc[0] += fv * w0.x; hacc[1] += fv * w0.y; hacc[2] += fv * w0.z; hacc[3] += fv * w0.w;
            hacc[4] += fv * w1.x; hacc[5] += fv * w1.y; hacc[6] += fv * w1.z; hacc[7] += fv * w1.w;
        }
        __syncthreads();
    }

    #pragma unroll
    for (int j = 0; j < 8; j++) {
        float v = hacc[j] + ba[d * 64 + fcol + j];
        hid[rr][fcol + j] = frelu(v);
    }
    __syncthreads();

    for (int o = tid; o < 320; o += 256) {
        int r2 = o / 10, c = o - r2 * 10;
        if (r2 < nrows) {
            float s = 0.f;
            #pragma unroll 16
            for (int l = 0; l < 64; l++) s += hid[r2][l] * Wb[((size_t)d * 64 + l) * 10 + c];
            outs[(size_t)rowidx[r2] * 10 + c] = s + bb[d * 10 + c];
        }
    }
}

// ---------------------------------------------------------------------------
extern "C" void kernel_launch(void* const* d_in, const int* in_sizes, int n_in,
                              void* d_out, int out_size, void* d_ws, size_t ws_size,
                              hipStream_t stream)
{
    const float* x     = (const float*)d_in[0];
    const float* W1    = (const float*)d_in[1];
    const float* b1    = (const float*)d_in[2];
    const float* gamma = (const float*)d_in[3];
    const float* beta  = (const float*)d_in[4];
    const float* Wd1   = (const float*)d_in[5];
    const float* bd1   = (const float*)d_in[6];
    const float* Wd2   = (const float*)d_in[7];
    const float* bd2   = (const float*)d_in[8];
    const float* Wa    = (const float*)d_in[9];
    const float* ba    = (const float*)d_in[10];
    const float* Wb    = (const float*)d_in[11];
    const float* bb    = (const float*)d_in[12];

    float* out    = (float*)d_out;
    float* outs   = out;
    float* outdom = out + (size_t)BATCH * 10;

    char* ws = (char*)d_ws;
    size_t off = 0;
    float*  h      = (float*)(ws + off);            off += (size_t)BATCH * HD * 4;
    unsigned short* W1hT  = (unsigned short*)(ws + off); off += (size_t)HD * 800 * 2;
    unsigned short* W1lT  = (unsigned short*)(ws + off); off += (size_t)HD * 800 * 2;
    unsigned short* Wd1hT = (unsigned short*)(ws + off); off += (size_t)HD * HD * 2;
    unsigned short* Wd1lT = (unsigned short*)(ws + off); off += (size_t)HD * HD * 2;
    double* s1     = (double*)(ws + off);           off += (size_t)BNB * HD * 8;
    double* s2     = (double*)(ws + off);           off += (size_t)BNB * HD * 8;
    float*  scale  = (float*)(ws + off);            off += HD * 4;
    float*  shift  = (float*)(ws + off);            off += HD * 4;
    size_t zoff = off;
    double* domacc = (double*)(ws + off);           off += (size_t)BATCH * 3 * 8;
    int*    cnt    = (int*)(ws + off);              off += 64;
    int*    fixmeta= (int*)(ws + off);              off += 64;
    size_t zbytes = off - zoff;
    int*    lists  = (int*)(ws + off);              off += (size_t)3 * BATCH * 4;
    int*    fixlist= (int*)(ws + off);              off += (size_t)BATCH * 4;

    hipMemsetAsync(ws + zoff, 0, zbytes, stream);

    split_wT<<<(HD * 800) / 256, 256, 0, stream>>>(W1, W1hT, W1lT, KIN, HD, 800);
    split_wT<<<(HD * HD) / 256, 256, 0, stream>>>(Wd1, Wd1hT, Wd1lT, HD, HD, HD);

    gemm_split<0><<<3072, 256, 0, stream>>>(x, W1hT, W1lT, b1, h,
                                            nullptr, nullptr, nullptr, nullptr,
                                            KIN, 800, 25, KIN);
    bnstats<<<BNB, 256, 0, stream>>>(h, s1, s2);
    bnfinal<<<3, 256, 0, stream>>>(s1, s2, gamma, beta, scale, shift);
    gemm_split<1><<<3072, 256, 0, stream>>>(h, Wd1hT, Wd1lT, bd1, nullptr,
                                            scale, shift, Wd2, domacc,
                                            HD, HD, 24, HD);
    domfinal_a<<<BATCH / 256, 256, 0, stream>>>(domacc, bd2, outdom, fixmeta, fixlist);
    fixrow<<<16, 256, 0, stream>>>(fixmeta, fixlist, h, scale, shift, Wd1, bd1, Wd2, bd2, outdom);
    domfinal_b<<<BATCH / 256, 256, 0, stream>>>(outdom, cnt, lists);
    dim3 eg(BATCH / 32, 3);
    expert_kernel<<<eg, 256, 0, stream>>>(h, scale, shift, cnt, lists,
                                          Wa, ba, Wb, bb, outs);
}